// Round 18
// baseline (278.000 us; speedup 1.0000x reference)
//
#include <hip/hip_runtime.h>

// N=100000 nodes, M=800000 edges, F_IN=64, F_E=16, H=64, T_NODE=2, T_EDGE=3.
// score == softmax over singleton axis == 1.0 exactly, so h3/h4/num are dead:
//   out[n] = h1[n] + sum_{e: dst=n} ( h2[src_e] + ef_e . W5[t_e] + b5[t_e] )
//
// R25 = R24 + barrier elimination in K2. The single __syncthreads coupled all
// 4 waves to the block's slowest wave (degree variance: Poisson-8 dsts, 44%
// need a second serial chunk). Now each wave owns SIXTEEN dsts = one full
// 16-row MFMA tile: it writes its own sa/sHb rows and MFMAs them itself --
// no cross-wave sharing, no barrier, waves fully decoupled. Per-dst MFMA
// count unchanged (16 MFMA / 16 dsts). Epilogue re-loads cnt32 (L2-hot)
// instead of LDS sCnt.
//  K0: zero-init + W1/W2 -> wtb + [W5;b5] -> wtb5.
//  K1: even blocks = slim gemm (h1b/h2b bf16 out); odd = scatter.
//  K2: gather (8-deep pairs) + per-wave MFMA, no barrier, plain-store.

#define CAP 16
#define OVF_CAP 32768

typedef __attribute__((ext_vector_type(8))) short short8;
typedef __attribute__((ext_vector_type(4))) float f32x4;

__device__ __forceinline__ float b2f(unsigned short u) {
    union { unsigned v; float f; } x; x.v = ((unsigned)u) << 16; return x.f;
}
__device__ __forceinline__ unsigned short f2b(float f) {
    union { float f; unsigned v; } x; x.f = f;
    unsigned u = x.v;
    unsigned r = (u + 0x7FFFu + ((u >> 16) & 1u)) >> 16;
    return (unsigned short)r;
}

// ---------------- K0: zero cnt block + one-shot weight tables ---------------
__global__ __launch_bounds__(256) void k0_init(
    int* __restrict__ zeroBase, int nZero,
    const float* __restrict__ W1, const float* __restrict__ W2,
    const float* __restrict__ W5, const float* __restrict__ b5,
    unsigned short* __restrict__ wtb, unsigned short* __restrict__ wtb5)
{
    int idx = blockIdx.x * 256 + threadIdx.x;
    if (idx < nZero) zeroBase[idx] = 0;
    if (idx < 16384) {
        int mm = idx >> 12;
        int r  = idx & 4095;
        int n  = r >> 6;
        int k  = r & 63;
        const float* src = ((mm < 2) ? W1 : W2) + (mm & 1) * 4096;
        wtb[mm * 4096 + n * 64 + k] = f2b(src[k * 64 + n]);
    }
    if (idx < 4096) {
        int h = idx >> 6;                 // 0..63 output col
        int j = idx & 63;                 // 0..63 K index
        float wv = 0.f;
        if (j < 48)      wv = W5[j * 64 + h];
        else if (j < 51) wv = b5[(j - 48) * 64 + h];
        wtb5[h * 64 + j] = f2b(wv);       // cols 51..63 zero
    }
}

// ---------------- K1: slim gemm (even blocks) || scatter (odd blocks) -------
__global__ __launch_bounds__(256) void k1_fused(
    const float* __restrict__ x, const int* __restrict__ nt,
    const unsigned short* __restrict__ wtb,
    const float* __restrict__ b1, const float* __restrict__ b2,
    const int* __restrict__ esrc, const int* __restrict__ edst,
    const int* __restrict__ etype,
    int* __restrict__ cnt32, int* __restrict__ ovfCnt,
    int4* __restrict__ ovf, int2* __restrict__ rec,
    unsigned short* __restrict__ h1b, unsigned short* __restrict__ h2b,
    int N, int M)
{
    // 72 = 64 + 8 pad: row stride 144 B -> 2-way bank alias (free)
    __shared__ __align__(16) unsigned short sx[128 * 72];     // 18 KB
    __shared__ int snt[128];

    int tid = threadIdx.x;

    if (blockIdx.x & 1) {
        // ---------------- scatter path: 1024 edges/block ---------------------
        int e0 = (blockIdx.x >> 1) * 1024 + tid;
        int dd[4], ssrc[4], tty[4];
        bool v[4];
#pragma unroll
        for (int j = 0; j < 4; ++j) {
            int e = e0 + j * 256;
            v[j] = e < M;
            int ec = v[j] ? e : 0;
            dd[j]   = edst[ec];
            ssrc[j] = esrc[ec];
            tty[j]  = etype[ec];
        }
        int pos[4];
#pragma unroll
        for (int j = 0; j < 4; ++j)
            if (v[j]) pos[j] = atomicAdd(&cnt32[dd[j]], 1);
#pragma unroll
        for (int j = 0; j < 4; ++j) {
            if (!v[j]) continue;
            int packed = ssrc[j] | (tty[j] << 20);
            int e = e0 + j * 256;
            if (pos[j] < CAP) {
                rec[dd[j] * CAP + pos[j]] = make_int2(packed, e);
            } else {
                int slot = atomicAdd(ovfCnt, 1);
                if (slot < OVF_CAP) ovf[slot] = make_int4(packed, e, dd[j], 0);
            }
        }
        return;
    }

    // ---------------- gemm path (B from global wtb) -------------------------
    int rowbase = (blockIdx.x >> 1) * 128;

    if (tid < 128) {
        int r = rowbase + tid;
        snt[tid] = (r < N) ? nt[r] : 0;
    }

    // stage x tile (contiguous rows, no perm)
    int fr = (tid & 15) * 4;
    int ir = tid >> 4;
#pragma unroll
    for (int it = 0; it < 8; ++it) {
        int i = it * 16 + ir;
        int r = rowbase + i;
        float4 v = make_float4(0.f, 0.f, 0.f, 0.f);
        if (r < N) v = *(const float4*)&x[(size_t)r * 64 + fr];
        ushort4 p;
        p.x = f2b(v.x); p.y = f2b(v.y); p.z = f2b(v.z); p.w = f2b(v.w);
        *(ushort4*)&sx[i * 72 + fr] = p;
    }
    __syncthreads();

    int lane = tid & 63;
    int wid  = tid >> 6;
    int q    = lane >> 4;
    int cc   = lane & 15;
    int m0   = wid * 32;

    f32x4 acc[4][2][4];   // [mat][s][t]
#pragma unroll
    for (int mm = 0; mm < 4; ++mm)
#pragma unroll
        for (int s = 0; s < 2; ++s)
#pragma unroll
            for (int t = 0; t < 4; ++t)
                acc[mm][s][t] = (f32x4){0.f, 0.f, 0.f, 0.f};

#pragma unroll
    for (int k0 = 0; k0 < 64; k0 += 32) {
        int ko = k0 + q * 8;
        short8 af0 = *(short8*)&sx[(m0 + cc) * 72 + ko];
        short8 af1 = *(short8*)&sx[(m0 + 16 + cc) * 72 + ko];
#pragma unroll
        for (int mm = 0; mm < 4; ++mm)
#pragma unroll
            for (int t = 0; t < 4; ++t) {
                // wtb[mm][n][k] == f2b(Wm[k][n]); 16B aligned (ko % 8 == 0)
                short8 bf = *(const short8*)
                    &wtb[mm * 4096 + (t * 16 + cc) * 64 + ko];
                acc[mm][0][t] = __builtin_amdgcn_mfma_f32_16x16x32_bf16(
                    af0, bf, acc[mm][0][t], 0, 0, 0);
                acc[mm][1][t] = __builtin_amdgcn_mfma_f32_16x16x32_bf16(
                    af1, bf, acc[mm][1][t], 0, 0, 0);
            }
    }

    float b1v[2][4], b2v[2][4];
#pragma unroll
    for (int ty = 0; ty < 2; ++ty)
#pragma unroll
        for (int t = 0; t < 4; ++t) {
            b1v[ty][t] = b1[ty * 64 + t * 16 + cc];
            b2v[ty][t] = b2[ty * 64 + t * 16 + cc];
        }

    // C/D layout: col = lane&15, row = quad*4 + reg
#pragma unroll
    for (int s = 0; s < 2; ++s)
#pragma unroll
        for (int reg = 0; reg < 4; ++reg) {
            int rl_ = m0 + s * 16 + q * 4 + reg;
            int r = rowbase + rl_;
            if (r < N) {
                int ty = snt[rl_];
#pragma unroll
                for (int t = 0; t < 4; ++t) {
                    float v1 = (ty ? acc[1][s][t][reg] : acc[0][s][t][reg])
                               + b1v[ty][t];
                    float v2 = (ty ? acc[3][s][t][reg] : acc[2][s][t][reg])
                               + b2v[ty][t];
                    h1b[(size_t)r * 64 + t * 16 + cc] = f2b(v1);
                    h2b[(size_t)r * 64 + t * 16 + cc] = f2b(v2);
                }
            }
        }
}

// ---------------- K2: gather + per-wave MFMA (64 dsts / block) --------------
// Each wave owns 16 dsts = one 16-row MFMA tile; NO __syncthreads anywhere
// (intra-wave LDS ordering is program-order).
// Phase 1 (8 pairs, 8-deep + conditional second chunk -- proven form):
//   accS -> sa[wave's rows] hi/lo bf16, accH -> sHb.
// Phase 2: C[16x64] = sa_tile * wtb5 (16 MFMAs); epilogue plain-stores
//   h1 + C + accH (atomic only for cnt>CAP rows shared with ovf fixup).
__global__ __launch_bounds__(256) void k2_gather_mm(
    const float* __restrict__ ef, const int2* __restrict__ rec,
    const int* __restrict__ cnt32,
    const float* __restrict__ W5, const float* __restrict__ b5,
    const unsigned short* __restrict__ wtb5,
    const int4* __restrict__ ovf, const int* __restrict__ ovfCnt,
    const unsigned short* __restrict__ h1b,
    const unsigned short* __restrict__ h2b, float* __restrict__ out,
    int N, int gatherBlocks, int ovfBlocks)
{
    __shared__ __align__(16) unsigned short sa[64 * 136];    // 17.4 KB A tiles
    __shared__ __align__(16) unsigned short sHb[64 * 66];    // 8.45 KB accH

    int tid = threadIdx.x;
    int lane = tid & 63;
    int wid = tid >> 6;

    if (blockIdx.x >= (unsigned)gatherBlocks) {
        // ---- overflow fixup: grid-stride waves over ovf list (rare) ----
        int novf = min(*ovfCnt, OVF_CAP);
        int gw = (blockIdx.x - gatherBlocks) * 4 + wid;
        int nw = ovfBlocks * 4;
        for (int ri = gw; ri < novf; ri += nw) {
            int4 o = ovf[ri];
            int s = o.x & 0xFFFFF;
            int t = (unsigned)o.x >> 20;
            float acc = b5[t * 64 + lane] + b2f(h2b[((size_t)s << 6) | lane]);
#pragma unroll
            for (int f = 0; f < 16; ++f)
                acc = fmaf(ef[(size_t)o.y * 16 + f],
                           W5[(t * 16 + f) * 64 + lane], acc);
            unsafeAtomicAdd(&out[(size_t)o.z * 64 + lane], acc);
        }
        return;
    }

    // ---- zero THIS WAVE's sa tail cols 52..63 and 116..127 (wave-local!):
    //      16 rows x 6 ushort4 = 96 tasks over 64 lanes, 2 rounds
    {
        ushort4 z; z.x = 0; z.y = 0; z.z = 0; z.w = 0;
#pragma unroll
        for (int k = 0; k < 2; ++k) {
            int idx = lane + k * 64;
            if (idx < 96) {
                int row = idx / 6;
                int w6 = idx - row * 6;
                int sp = (w6 < 3) ? (52 + w6 * 4) : (116 + (w6 - 3) * 4);
                *(ushort4*)&sa[(wid * 16 + row) * 136 + sp] = z;
            }
        }
    }

    // ---- phase 1: 16 dsts per wave, processed in pipelined pairs ----
    int myt = (lane < 48) ? (lane >> 4) : (lane - 48);
    unsigned myf = lane & 15;
    bool fl = lane < 48;
    int wbase = blockIdx.x * 64 + wid * 16;

    int cnts[16];
#pragma unroll
    for (int g = 0; g < 16; ++g) {
        int d = wbase + g;
        cnts[g] = (d < N) ? cnt32[d] : 0;
    }

#pragma unroll 1
    for (int gp = 0; gp < 16; gp += 2) {
        int dA = wbase + gp, dB = dA + 1;
        int dgA = min(cnts[gp], CAP);
        int dgB = min(cnts[gp + 1], CAP);
        unsigned baseA = (unsigned)(dA < N ? dA : 0) * CAP;
        unsigned baseB = (unsigned)(dB < N ? dB : 0) * CAP;

        // issue both rec batches (wave-uniform -> scalar loads)
        int2 rA[8], rB[8];
#pragma unroll
        for (int j = 0; j < 8; ++j) rA[j] = rec[baseA + j];
#pragma unroll
        for (int j = 0; j < 8; ++j) rB[j] = rec[baseB + j];

        // issue both gather batches (stale slots masked to address 0)
        float hvA[8], evA[8], hvB[8], evB[8];
#pragma unroll
        for (int j = 0; j < 8; ++j) {
            bool ok = j < dgA;
            unsigned s = ok ? ((unsigned)rA[j].x & 0xFFFFFu) : 0u;
            unsigned e = ok ? (unsigned)rA[j].y : 0u;
            hvA[j] = b2f(h2b[((size_t)s << 6) | (unsigned)lane]);
            evA[j] = ef[(e << 4) | myf];
        }
#pragma unroll
        for (int j = 0; j < 8; ++j) {
            bool ok = j < dgB;
            unsigned s = ok ? ((unsigned)rB[j].x & 0xFFFFFu) : 0u;
            unsigned e = ok ? (unsigned)rB[j].y : 0u;
            hvB[j] = b2f(h2b[((size_t)s << 6) | (unsigned)lane]);
            evB[j] = ef[(e << 4) | myf];
        }

        float accHA = 0.f, accSA = 0.f, accHB = 0.f, accSB = 0.f;
#pragma unroll
        for (int j = 0; j < 8; ++j) {
            bool okA = j < dgA;
            int tA = (int)((unsigned)rA[j].x >> 20);
            accHA += okA ? hvA[j] : 0.f;
            float vA = fl ? evA[j] : 1.0f;
            accSA += (okA && tA == myt) ? vA : 0.f;
            bool okB = j < dgB;
            int tB = (int)((unsigned)rB[j].x >> 20);
            accHB += okB ? hvB[j] : 0.f;
            float vB = fl ? evB[j] : 1.0f;
            accSB += (okB && tB == myt) ? vB : 0.f;
        }

        // second chunks (deg > 8): on-demand clamped loads (44% of dsts)
        if (dgA > 8) {
            int2 r2[8];
#pragma unroll
            for (int j = 0; j < 8; ++j)
                r2[j] = rec[baseA + (unsigned)min(8 + j, dgA - 1)];
#pragma unroll
            for (int j = 0; j < 8; ++j) {
                unsigned s = (unsigned)r2[j].x & 0xFFFFFu;
                float hv = b2f(h2b[((size_t)s << 6) | (unsigned)lane]);
                float evv = ef[((unsigned)r2[j].y << 4) | myf];
                int t = (int)((unsigned)r2[j].x >> 20);
                bool ok = (8 + j) < dgA;
                accHA += ok ? hv : 0.f;
                float v = fl ? evv : 1.0f;
                accSA += (ok && t == myt) ? v : 0.f;
            }
        }
        if (dgB > 8) {
            int2 r2[8];
#pragma unroll
            for (int j = 0; j < 8; ++j)
                r2[j] = rec[baseB + (unsigned)min(8 + j, dgB - 1)];
#pragma unroll
            for (int j = 0; j < 8; ++j) {
                unsigned s = (unsigned)r2[j].x & 0xFFFFFu;
                float hv = b2f(h2b[((size_t)s << 6) | (unsigned)lane]);
                float evv = ef[((unsigned)r2[j].y << 4) | myf];
                int t = (int)((unsigned)r2[j].x >> 20);
                bool ok = (8 + j) < dgB;
                accHB += ok ? hv : 0.f;
                float v = fl ? evv : 1.0f;
                accSB += (ok && t == myt) ? v : 0.f;
            }
        }

        int wdA = wid * 16 + gp, wdB = wdA + 1;
        if (lane < 52) {
            unsigned short hiA = f2b(accSA);
            sa[wdA * 136 + lane] = hiA;
            sa[wdA * 136 + 64 + lane] = f2b(accSA - b2f(hiA));
            unsigned short hiB = f2b(accSB);
            sa[wdB * 136 + lane] = hiB;
            sa[wdB * 136 + 64 + lane] = f2b(accSB - b2f(hiB));
        }
        sHb[wdA * 66 + lane] = f2b(accHA);
        sHb[wdB * 66 + lane] = f2b(accHB);
    }
    // NO barrier: this wave reads back only its own sa/sHb rows (program
    // order within a wave; compiler inserts the lgkmcnt waits).

    // ---- phase 2: C[16x64] via 16 MFMAs on this wave's own tile ----
    int q  = lane >> 4;
    int cc = lane & 15;
    int rowb = wid * 16;

    // prefetch h1 epilogue values + per-row cnt (hide under MFMA)
    float h1v[4][4];
    int cq[4];
#pragma unroll
    for (int reg = 0; reg < 4; ++reg) {
        int d = wbase + q * 4 + reg;
        unsigned dc = (unsigned)((d < N) ? d : 0);
        cq[reg] = cnt32[dc];
#pragma unroll
        for (int t = 0; t < 4; ++t)
            h1v[reg][t] = b2f(h1b[(size_t)dc * 64 + t * 16 + cc]);
    }

    f32x4 acc[4];
#pragma unroll
    for (int t = 0; t < 4; ++t) acc[t] = (f32x4){0.f, 0.f, 0.f, 0.f};
#pragma unroll
    for (int k0 = 0; k0 < 128; k0 += 32) {
        int ko = k0 + q * 8;
        int kb = ko & 63;
        short8 af = *(short8*)&sa[(rowb + cc) * 136 + ko];
#pragma unroll
        for (int t = 0; t < 4; ++t) {
            short8 bf = *(const short8*)&wtb5[(t * 16 + cc) * 64 + kb];
            acc[t] = __builtin_amdgcn_mfma_f32_16x16x32_bf16(
                af, bf, acc[t], 0, 0, 0);
        }
    }

    // C/D layout: col = lane&15, row = quad*4 + reg
#pragma unroll
    for (int reg = 0; reg < 4; ++reg) {
        int rl = q * 4 + reg;
        int d = wbase + rl;
        if (d < N) {
            bool atom = cq[reg] > CAP;   // row shared with ovf fixup
#pragma unroll
            for (int t = 0; t < 4; ++t) {
                int c = t * 16 + cc;
                float v = acc[t][reg] + b2f(sHb[(rowb + rl) * 66 + c])
                        + h1v[reg][t];
                float* p = &out[(size_t)d * 64 + c];
                if (atom) unsafeAtomicAdd(p, v);
                else      *p = v;
            }
        }
    }
}

extern "C" void kernel_launch(void* const* d_in, const int* in_sizes, int n_in,
                              void* d_out, int out_size, void* d_ws, size_t ws_size,
                              hipStream_t stream) {
    const float* x  = (const float*)d_in[0];
    const float* ef = (const float*)d_in[1];
    const int* nt   = (const int*)d_in[2];
    const int* es   = (const int*)d_in[3];
    const int* ed   = (const int*)d_in[4];
    const int* et   = (const int*)d_in[5];
    const float* W1 = (const float*)d_in[6];
    const float* b1 = (const float*)d_in[7];
    const float* W2 = (const float*)d_in[8];
    const float* b2 = (const float*)d_in[9];
    // d_in[10..13] = W3,b3,W4,b4 dead (score == 1.0)
    const float* W5 = (const float*)d_in[14];
    const float* b5 = (const float*)d_in[15];

    int N = in_sizes[2];
    int M = in_sizes[3];

    char* w = (char*)d_ws;
    size_t off = 0;
    unsigned short* h2b = (unsigned short*)(w + off); off += (size_t)N * 64 * 2;  // 12.8 MB
    off = (off + 255) & ~(size_t)255;
    unsigned short* h1b = (unsigned short*)(w + off); off += (size_t)N * 64 * 2;  // 12.8 MB
    off = (off + 255) & ~(size_t)255;
    int2* rec = (int2*)(w + off); off += (size_t)N * CAP * 8;                     // 12.8 MB
    off = (off + 255) & ~(size_t)255;
    int4* ovf = (int4*)(w + off); off += (size_t)OVF_CAP * 16;                    // 0.5 MB
    off = (off + 255) & ~(size_t)255;
    unsigned short* wtb = (unsigned short*)(w + off); off += 4 * 4096 * 2;        // 32 KB
    off = (off + 255) & ~(size_t)255;
    unsigned short* wtb5 = (unsigned short*)(w + off); off += 64 * 64 * 2;        // 8 KB
    off = (off + 255) & ~(size_t)255;
    // zero block: [ovfCnt:1 int][pad->64 B][cnt32: N ints]
    int* ovfCnt = (int*)(w + off);
    int* cnt32  = (int*)(w + off + 64);
    int nZero = 16 + N;                      // ints: ovfCnt+pad + cnt32

    float* out = (float*)d_out;

    int initBlocks = (nZero + 255) / 256;    // 391 (also covers wtb/wtb5)
    k0_init<<<initBlocks, 256, 0, stream>>>(
        ovfCnt, nZero, W1, W2, W5, b5, wtb, wtb5);

    int gemmBlocks    = (N + 127) / 128;     // 782
    int scatterBlocks = (M + 1023) / 1024;   // 782
    int gb1 = 2 * max(gemmBlocks, scatterBlocks);
    k1_fused<<<gb1, 256, 0, stream>>>(
        x, nt, wtb, b1, b2, es, ed, et,
        cnt32, ovfCnt, ovf, rec, h1b, h2b, N, M);

    int gatherBlocks = (N + 63) / 64;        // 1563
    int ovfBlocks = 32;
    k2_gather_mm<<<gatherBlocks + ovfBlocks, 256, 0, stream>>>(
        ef, rec, cnt32, W5, b5, wtb5, ovf, ovfCnt, h1b, h2b, out,
        N, gatherBlocks, ovfBlocks);
}